// Round 6
// baseline (484.813 us; speedup 1.0000x reference)
//
#include <hip/hip_runtime.h>
#include <float.h>

// Shapes (fixed by the problem)
#define Bsz 2
#define Ssz 4096
#define Hsz 12
#define Gsz 64
#define Wsz 513
#define Csz (Gsz + Wsz)       // 577 channels
#define ROW (Hsz * Csz)       // 6924 floats per (b,s) row
#define HALF 256
#define RPB 8                 // rows per block
#define NWIN (RPB - 1 + Wsz)  // 520 window slots

// Workspace layout (floats)
#define PSUM_SZ ((size_t)Bsz * Ssz)   // 8192
#define GACC_SZ ((size_t)Bsz * Gsz)   // 128

// K1: aligned-parity loads + per-thread register ring.
// Thread t<145 nominally owns channels [4t,4t+4). For head h (p=h&3) it
// loads the ALIGNED float4 at flat offset h*577-p+4t, covering channels
// 4t-p..4t+3-p. Edge masks (j<p zeroed at t==0, j>p zeroed at t==144)
// make each head's 577 channels covered exactly once, with every load
// 16B-aligned and in-bounds. Window slot = ch-64+r = 4t-67+(r+3-p+j):
// the index s=r+3-p+j is compile-time under full unroll -> 14-register
// ring, r cancels. 96 independent aligned loads/thread, 14 ds_adds at
// the end. Wave 0 additionally tracks global channels (c<64) in an
// r-independent 7-ring (wave-uniform dual path).
__global__ __launch_bounds__(192, 4) void k1_fused(
    const float* __restrict__ probs, const float* __restrict__ mask,
    float* __restrict__ psum, float* __restrict__ gacc)
{
    __shared__ float win[NWIN];     // 2080 B
    __shared__ float gl[Gsz];       // 256 B
    const int t = threadIdx.x;
    const int row0 = blockIdx.x * RPB;
    const int b = row0 / Ssz;

    for (int u = t; u < NWIN; u += 192) win[u] = 0.f;
    if (t < Gsz) gl[t] = 0.f;

    float scl[RPB];
    #pragma unroll
    for (int r = 0; r < RPB; ++r)
        scl[r] = (mask[row0 + r] < 0.f) ? 0.f : 1.f;

    // edge factors: t==0 kills j<p, t==144 kills j>p
    const float f0   = (t == 0)   ? 0.f : 1.f;
    const float f144 = (t == 144) ? 0.f : 1.f;
    // mp[p][j]: j<p -> f0 ; j>p -> f144 ; j==p -> 1
    float mp[4][4];
    #pragma unroll
    for (int p = 0; p < 4; ++p)
        #pragma unroll
        for (int j = 0; j < 4; ++j)
            mp[p][j] = (j < p) ? f0 : ((j > p) ? f144 : 1.f);

    float ring_w[14];
    #pragma unroll
    for (int s = 0; s < 14; ++s) ring_w[s] = 0.f;

    const float* __restrict__ base = probs + (size_t)row0 * ROW + 4 * t;

    if (t < 64) {
        // dual path: also accumulate global channels (r-independent ring)
        float ring_g[7];
        float mg[7], mw[7];
        #pragma unroll
        for (int i = 0; i < 7; ++i) {
            const int ch = 4 * t + i - 3;
            ring_g[i] = 0.f;
            mg[i] = (ch >= 0 && ch < Gsz) ? 1.f : 0.f;
            mw[i] = 1.f - mg[i];
        }
        #pragma unroll
        for (int r = 0; r < RPB; ++r) {
            const float sr = scl[r];
            const float* rp = base + (size_t)r * ROW;
            #pragma unroll
            for (int h = 0; h < Hsz; ++h) {
                const int p = h & 3;
                float4 v = *(const float4*)(rp + (h * Csz - p));
                const int ib = 3 - p;          // ring_g base
                const int sb = r + 3 - p;      // ring_w base
                float vj;
                vj = v.x * (mp[p][0] * sr); ring_g[ib+0] += vj * mg[ib+0]; ring_w[sb+0] += vj * mw[ib+0];
                vj = v.y * (mp[p][1] * sr); ring_g[ib+1] += vj * mg[ib+1]; ring_w[sb+1] += vj * mw[ib+1];
                vj = v.z * (mp[p][2] * sr); ring_g[ib+2] += vj * mg[ib+2]; ring_w[sb+2] += vj * mw[ib+2];
                vj = v.w * (mp[p][3] * sr); ring_g[ib+3] += vj * mg[ib+3]; ring_w[sb+3] += vj * mw[ib+3];
            }
        }
        __syncthreads();   // win/gl zero-init visible
        #pragma unroll
        for (int i = 0; i < 7; ++i) {
            const int ch = 4 * t + i - 3;
            if (ch >= 0 && ch < Gsz) atomicAdd(&gl[ch], ring_g[i]);
        }
    } else if (t < 145) {
        // pure window path
        #pragma unroll
        for (int r = 0; r < RPB; ++r) {
            const float sr = scl[r];
            const float* rp = base + (size_t)r * ROW;
            #pragma unroll
            for (int h = 0; h < Hsz; ++h) {
                const int p = h & 3;
                float4 v = *(const float4*)(rp + (h * Csz - p));
                const int sb = r + 3 - p;
                ring_w[sb+0] += v.x * (mp[p][0] * sr);
                ring_w[sb+1] += v.y * (mp[p][1] * sr);
                ring_w[sb+2] += v.z * (mp[p][2] * sr);
                ring_w[sb+3] += v.w * (mp[p][3] * sr);
            }
        }
        __syncthreads();
    } else {
        __syncthreads();
    }

    // flush window ring: slot w = 4t - 67 + s
    #pragma unroll
    for (int s = 0; s < 14; ++s) {
        const int w = 4 * t - 67 + s;
        if (w >= 0 && w < NWIN) atomicAdd(&win[w], ring_w[s]);
    }
    __syncthreads();

    // global flush: window slot w -> output i = s0 + w - 256
    const int s0 = row0 - b * Ssz;
    for (int w = t; w < NWIN; w += 192) {
        const int i = s0 + w - HALF;
        if (i >= 0 && i < Ssz) atomicAdd(&psum[b * Ssz + i], win[w]);
    }
    if (t < Gsz) atomicAdd(&gacc[b * Gsz + t], gl[t]);
}

// K4: fused scatter (honors index arrays) + per-batch max + scores + mask.
__global__ __launch_bounds__(1024) void k4_final(
    const float* __restrict__ psum, const float* __restrict__ gacc,
    const float* __restrict__ thr_p,
    const int* __restrict__ loc_b, const int* __restrict__ loc_i,
    const int* __restrict__ glob_b, const int* __restrict__ glob_i,
    int n_idx, float* __restrict__ out)
{
    __shared__ float p_lds[Ssz];   // 16 KiB
    __shared__ float red[16];
    const int b = blockIdx.x;
    const int t = threadIdx.x;
    const float4* p4 = (const float4*)(psum + (size_t)b * Ssz);

    ((float4*)p_lds)[t] = p4[t];   // 1024 float4 = 4096 floats
    __syncthreads();

    if (t < n_idx && loc_b[t] == b)
        atomicAdd(&p_lds[loc_i[t]], gacc[glob_b[t] * Gsz + glob_i[t]]);
    __syncthreads();

    float m = -FLT_MAX;
    for (int i = t; i < Ssz; i += 1024) m = fmaxf(m, p_lds[i]);
    #pragma unroll
    for (int off = 32; off >= 1; off >>= 1) m = fmaxf(m, __shfl_down(m, off, 64));

    const int wave = t >> 6, lane = t & 63;
    if (lane == 0) red[wave] = m;
    __syncthreads();
    if (t == 0) {
        float mm = red[0];
        #pragma unroll
        for (int w = 1; w < 16; ++w) mm = fmaxf(mm, red[w]);
        red[0] = mm;
    }
    __syncthreads();
    const float mx = red[0];
    const float thr = fmaxf(1e-5f, thr_p[0]);

    for (int i = t; i < Ssz; i += 1024) {
        float sc = p_lds[i] / mx;
        out[(size_t)Bsz * Ssz + (size_t)b * Ssz + i] = sc;        // scores (output 1)
        out[(size_t)b * Ssz + i] = (sc < thr) ? -10000.f : 0.f;   // mask (output 0)
    }
}

extern "C" void kernel_launch(void* const* d_in, const int* in_sizes, int n_in,
                              void* d_out, int out_size, void* d_ws, size_t ws_size,
                              hipStream_t stream)
{
    const float* mask  = (const float*)d_in[0];
    const float* probs = (const float*)d_in[1];
    const float* thr   = (const float*)d_in[2];
    // d_in[3] = max_num_global_attn_indices (hard-coded as Gsz)
    const int* loc_b  = (const int*)d_in[4];
    const int* loc_i  = (const int*)d_in[5];
    const int* glob_b = (const int*)d_in[6];
    const int* glob_i = (const int*)d_in[7];
    const int n_idx = in_sizes[4];

    float* psum = (float*)d_ws;
    float* gacc = psum + PSUM_SZ;
    float* out  = (float*)d_out;

    // zero psum + gacc (ws is poisoned 0xAA before every launch)
    hipMemsetAsync(psum, 0, (PSUM_SZ + GACC_SZ) * sizeof(float), stream);

    k1_fused<<<dim3(Bsz * Ssz / RPB), dim3(192), 0, stream>>>(probs, mask, psum, gacc);
    k4_final<<<dim3(Bsz), dim3(1024), 0, stream>>>(psum, gacc, thr,
                                                   loc_b, loc_i, glob_b, glob_i,
                                                   n_idx, out);
}